// Round 10
// baseline (1674.463 us; speedup 1.0000x reference)
//
#include <hip/hip_runtime.h>

// MUTAN fused bilinear (low-rank Tucker) + ReLU + LayerNorm, MI355X gfx950.
// Round 10: ABLATION ROUND. Production = round-9 kernel (unchanged, correct).
// Plus two scratch-writing ablation variants (REPS=2 so they dominate top-5):
//   MODE 1 (noBar): all s_barrier removed, work identical -> lockstep cost.
//   MODE 2 (noDS):  ds_read removed (regs reused), staging/B/MFMA/barriers
//                   kept -> LDS-read critical-path share.

typedef unsigned short u16;
typedef __attribute__((ext_vector_type(8))) short bf16x8;   // 8 bf16 = 4 VGPRs
typedef __attribute__((ext_vector_type(4))) float f32x4;    // MFMA C/D

constexpr int Bq = 4096;   // batch
constexpr int D  = 1024;   // contraction dim
constexpr int Zq = 1024;   // output dim
constexpr int Rk = 16;     // rank

typedef const __attribute__((address_space(1))) void* gas_t;
typedef __attribute__((address_space(3))) void* las_t;

__device__ __forceinline__ u16 f2b(float f) {
  union { float f; unsigned u; } c; c.f = f;
  unsigned r = (c.u + 0x7FFFu + ((c.u >> 16) & 1u)) >> 16;  // RNE
  return (u16)r;
}

// ---- prep: hd/hp [4096][1024] f32 -> fragment-major bf16 ----
__global__ __launch_bounds__(256) void fm_pack_A(const float* __restrict__ src,
                                                 u16* __restrict__ dst) {
  const int g  = blockIdx.x * 256 + threadIdx.x;      // chunk id
  const int c  = g & 1023;
  const int kt = (g >> 10) & 15;
  const int bx = g >> 14;
  const int l  = c & 63;
  const int kk = (c >> 6) & 1;
  const int mf = (c >> 7) & 3;
  const int wm = (c >> 9) & 1;
  const int row = wm * 64 + mf * 16 + (l & 15);
  const int kel = kk * 32 + ((l >> 4) << 3);
  const float* s = src + (size_t)(bx * 128 + row) * D + kt * 64 + kel;
  const float4 f0 = *(const float4*)s;
  const float4 f1 = *(const float4*)(s + 4);
  union { u16 h[8]; uint4 u; } o;
  o.h[0] = f2b(f0.x); o.h[1] = f2b(f0.y); o.h[2] = f2b(f0.z); o.h[3] = f2b(f0.w);
  o.h[4] = f2b(f1.x); o.h[5] = f2b(f1.y); o.h[6] = f2b(f1.z); o.h[7] = f2b(f1.w);
  *(uint4*)(dst + (size_t)g * 8) = o.u;
}

// ---- prep: U/V [r][k][z] f32 -> fragment-major bf16 ----
__global__ __launch_bounds__(256) void fm_pack_B(const float* __restrict__ src,
                                                 u16* __restrict__ dst) {
  const int g  = blockIdx.x * 256 + threadIdx.x;      // chunk id
  const int c  = g & 1023;
  const int kt = (g >> 10) & 15;
  const int jt = (g >> 14) & 7;
  const int r  = g >> 17;
  const int l  = c & 63;
  const int kk = (c >> 6) & 1;
  const int nf = (c >> 7) & 1;
  const int wn = (c >> 8) & 3;
  const int j  = jt * 128 + wn * 32 + nf * 16 + (l & 15);
  const int kg = kt * 64 + kk * 32 + ((l >> 4) << 3);
  const float* s = src + (size_t)r * (D * Zq) + (size_t)kg * Zq + j;
  union { u16 h[8]; uint4 u; } o;
  #pragma unroll
  for (int e = 0; e < 8; ++e) o.h[e] = f2b(s[(size_t)e * Zq]);
  *(uint4*)(dst + (size_t)g * 8) = o.u;
}

#define GLDS(src, dst) __builtin_amdgcn_global_load_lds((gas_t)(src), (las_t)(dst), 16, 0, 0)
#define SFENCE() __builtin_amdgcn_sched_barrier(0)
#define MFMA __builtin_amdgcn_mfma_f32_16x16x32_bf16
// MODE-aware barrier: MODE 1 strips all barriers
#define BARM() do { if (MODE != 1) __builtin_amdgcn_s_barrier(); } while (0)

// one K-step = 4 phases; buf is compile-time (= s&1)
#define STEP(buf, s) do {                                                        \
  const u16* tA = sT[buf][0];                                                    \
  const u16* tB = sT[buf][1];                                                    \
  const bool pf1 = (s) + 1 < 256;                                                \
  const bool pf2 = (s) + 2 < 256;                                                \
  const int kn2 = ((s) + 2) & 15;                                                \
  const u16* upn = Ub + (size_t)(((s)+1) >> 4) * rstride + (((s)+1) & 15) * 8192;\
  const u16* vpn = Vb + (size_t)(((s)+1) >> 4) * rstride + (((s)+1) & 15) * 8192;\
  _Pragma("unroll")                                                              \
  for (int p = 0; p < 4; ++p) {                                                  \
    const int kk = p >> 1, mh = (p & 1) << 1;                                    \
    const int r0 = (((wm * 4 + mh) * 2 + kk) * 64 + lane) * 8;                   \
    bf16x8 a0, a1, b0, b1;                                                       \
    if (MODE != 2) {                                                             \
      a0 = *(const bf16x8*)(tA + r0);                                            \
      a1 = *(const bf16x8*)(tA + r0 + 1024);                                     \
      b0 = *(const bf16x8*)(tB + r0);                                            \
      b1 = *(const bf16x8*)(tB + r0 + 1024);                                     \
    } else {                     /* noDS: reuse B regs as A operands */          \
      a0 = bu[0][kk]; a1 = bv[0][kk]; b0 = bu[1][kk]; b1 = bv[1][kk];            \
    }                                                                            \
    if (p == 2 && pf1) {         /* kk0 B-regs free after ph1 -> reload (s+1) */ \
      bu[0][0] = *(const bf16x8*)(upn + bco[0][0]);                              \
      bu[1][0] = *(const bf16x8*)(upn + bco[1][0]);                              \
      bv[0][0] = *(const bf16x8*)(vpn + bco[0][0]);                              \
      bv[1][0] = *(const bf16x8*)(vpn + bco[1][0]);                              \
    }                                                                            \
    SFENCE();                                                                    \
    BARM();                                                                      \
    asm volatile("s_waitcnt lgkmcnt(0)" ::: "memory");                           \
    SFENCE();                                                                    \
    __builtin_amdgcn_s_setprio(1);                                               \
    au[mh][0]     = MFMA(a0, bu[0][kk], au[mh][0], 0, 0, 0);                     \
    av[mh][0]     = MFMA(b0, bv[0][kk], av[mh][0], 0, 0, 0);                     \
    au[mh][1]     = MFMA(a0, bu[1][kk], au[mh][1], 0, 0, 0);                     \
    av[mh][1]     = MFMA(b0, bv[1][kk], av[mh][1], 0, 0, 0);                     \
    au[mh + 1][0] = MFMA(a1, bu[0][kk], au[mh + 1][0], 0, 0, 0);                 \
    av[mh + 1][0] = MFMA(b1, bv[0][kk], av[mh + 1][0], 0, 0, 0);                 \
    au[mh + 1][1] = MFMA(a1, bu[1][kk], au[mh + 1][1], 0, 0, 0);                 \
    av[mh + 1][1] = MFMA(b1, bv[1][kk], av[mh + 1][1], 0, 0, 0);                 \
    __builtin_amdgcn_s_setprio(0);                                               \
    if (p == 3) {                                                                \
      if (pf1) {                 /* kk1 B-regs free after ph3 MFMAs */           \
        bu[0][1] = *(const bf16x8*)(upn + bco[0][1]);                            \
        bu[1][1] = *(const bf16x8*)(upn + bco[1][1]);                            \
        bv[0][1] = *(const bf16x8*)(vpn + bco[0][1]);                            \
        bv[1][1] = *(const bf16x8*)(vpn + bco[1][1]);                            \
      }                                                                          \
      if (pf2) {                                                                 \
        GLDS(hdp + kn2 * 8192 + c0 * 8, &sT[buf][0][c0 * 8]);                    \
        GLDS(hdp + kn2 * 8192 + c1 * 8, &sT[buf][0][c1 * 8]);                    \
        GLDS(hpp + kn2 * 8192 + c0 * 8, &sT[buf][1][c0 * 8]);                    \
        GLDS(hpp + kn2 * 8192 + c1 * 8, &sT[buf][1][c1 * 8]);                    \
        SFENCE();                                                                \
        asm volatile("s_waitcnt vmcnt(12)" ::: "memory");                        \
      } else if ((s) == 254) {                                                   \
        SFENCE();                                                                \
        asm volatile("s_waitcnt vmcnt(8)" ::: "memory");                         \
      } else {                                                                   \
        SFENCE();                                                                \
        asm volatile("s_waitcnt vmcnt(0)" ::: "memory");                         \
      }                                                                          \
    }                                                                            \
    SFENCE();                                                                    \
    BARM();                                                                      \
    SFENCE();                                                                    \
  }                                                                              \
} while (0)

// ---- main: fused bilinear, bf16 MFMA 16x16x32 ----
// MODE 0 = production (round 9). MODE 1 = noBar ablation. MODE 2 = noDS.
template<int MODE, int REPS>
__global__ __launch_bounds__(512, 2) void fused_bilinear(
    const u16* __restrict__ hdf, const u16* __restrict__ hpf,
    const u16* __restrict__ Uf, const u16* __restrict__ Vf,
    float* __restrict__ outp)
{
  __shared__ __align__(16) u16 sT[2][2][128 * 64];   // 64 KB

  const int tid  = threadIdx.x;
  const int lane = tid & 63;
  const int wv   = tid >> 6;
  const int wm   = wv >> 2;               // 0..1
  const int wn   = wv & 3;                // 0..3

  const int bx = blockIdx.x;              // 0..31 (XCD = bx%8)
  const int jt = blockIdx.y;              // 0..7

  const u16* hdp = hdf + (size_t)bx * 16 * 8192;     // [kt][1024 chunks][8]
  const u16* hpp = hpf + (size_t)bx * 16 * 8192;
  const u16* Ub  = Uf + (size_t)jt * 16 * 8192;      // + r*rstride + kt*8192
  const u16* Vb  = Vf + (size_t)jt * 16 * 8192;
  const size_t rstride = (size_t)8 * 16 * 8192;

  const int c0 = wv * 128 + lane;
  const int c1 = c0 + 64;

  int bco[2][2];
  #pragma unroll
  for (int nf = 0; nf < 2; ++nf)
    #pragma unroll
    for (int kk = 0; kk < 2; ++kk)
      bco[nf][kk] = (((wn * 2 + nf) * 2 + kk) * 64 + lane) * 8;

  f32x4 acc[4][2], au[4][2], av[4][2];
  #pragma unroll
  for (int mf = 0; mf < 4; ++mf)
    #pragma unroll
    for (int nf = 0; nf < 2; ++nf) {
      acc[mf][nf] = (f32x4){0.f, 0.f, 0.f, 0.f};
      au[mf][nf]  = (f32x4){0.f, 0.f, 0.f, 0.f};
      av[mf][nf]  = (f32x4){0.f, 0.f, 0.f, 0.f};
    }

  bf16x8 bu[2][2], bv[2][2];   // [nf][kk], single set, recycled in-step

  // prologue: stage steps 0,1; load B(0); drain once; barrier.
  GLDS(hdp + 0 * 8192 + c0 * 8, &sT[0][0][c0 * 8]);
  GLDS(hdp + 0 * 8192 + c1 * 8, &sT[0][0][c1 * 8]);
  GLDS(hpp + 0 * 8192 + c0 * 8, &sT[0][1][c0 * 8]);
  GLDS(hpp + 0 * 8192 + c1 * 8, &sT[0][1][c1 * 8]);
  GLDS(hdp + 1 * 8192 + c0 * 8, &sT[1][0][c0 * 8]);
  GLDS(hdp + 1 * 8192 + c1 * 8, &sT[1][0][c1 * 8]);
  GLDS(hpp + 1 * 8192 + c0 * 8, &sT[1][1][c0 * 8]);
  GLDS(hpp + 1 * 8192 + c1 * 8, &sT[1][1][c1 * 8]);
  #pragma unroll
  for (int nf = 0; nf < 2; ++nf)
    #pragma unroll
    for (int kk = 0; kk < 2; ++kk) {
      bu[nf][kk] = *(const bf16x8*)(Ub + bco[nf][kk]);
      bv[nf][kk] = *(const bf16x8*)(Vb + bco[nf][kk]);
    }
  SFENCE();
  asm volatile("s_waitcnt vmcnt(0)" ::: "memory");
  SFENCE();
  BARM(); SFENCE();

  #pragma unroll 1
  for (int rep = 0; rep < REPS; ++rep) {
    #pragma unroll 1
    for (int it = 0; it < 128; ++it) {
      const int s0 = it * 2;
      const int s1 = s0 + 1;

      STEP(0, s0);
      STEP(1, s1);

      // rank boundary every 16 steps (always lands on odd s1)
      if ((s1 & 15) == 15) {
        #pragma unroll
        for (int mf = 0; mf < 4; ++mf)
          #pragma unroll
          for (int nf = 0; nf < 2; ++nf) {
            #pragma unroll
            for (int i = 0; i < 4; ++i)
              acc[mf][nf][i] += au[mf][nf][i] * av[mf][nf][i];
            au[mf][nf] = (f32x4){0.f, 0.f, 0.f, 0.f};
            av[mf][nf] = (f32x4){0.f, 0.f, 0.f, 0.f};
          }
      }
    }
  }

  // epilogue: store RAW sum (ReLU in LN). C/D: col = lane&15, row = 4*(lane>>4)+i.
  const int brow = bx * 128;
  const int jcol = jt * 128;
  #pragma unroll
  for (int mf = 0; mf < 4; ++mf)
    #pragma unroll
    for (int nf = 0; nf < 2; ++nf) {
      const int gr = brow + wm * 64 + mf * 16 + ((lane >> 4) << 2);
      const int gc = jcol + wn * 32 + nf * 16 + (lane & 15);
      #pragma unroll
      for (int i = 0; i < 4; ++i)
        outp[(size_t)(gr + i) * Zq + gc] = acc[mf][nf][i];
    }
}

// ---- LayerNorm: z = relu(p); LN(z) -> out, in place. jnp.var ddof=0. ----
__global__ __launch_bounds__(256) void ln_rows(float* __restrict__ out,
    const float* __restrict__ gamma, const float* __restrict__ beta)
{
  const int row = blockIdx.x;
  const int t = threadIdx.x;
  float* o = out + (size_t)row * Zq;
  float4 v = ((const float4*)o)[t];
  v.x = fmaxf(v.x, 0.f); v.y = fmaxf(v.y, 0.f);
  v.z = fmaxf(v.z, 0.f); v.w = fmaxf(v.w, 0.f);
  float s = v.x + v.y + v.z + v.w;
  float q = v.x * v.x + v.y * v.y + v.z * v.z + v.w * v.w;
  #pragma unroll
  for (int off = 32; off > 0; off >>= 1) {
    s += __shfl_xor(s, off);
    q += __shfl_xor(q, off);
  }
  __shared__ float ss[4], sq[4];
  if ((t & 63) == 0) { ss[t >> 6] = s; sq[t >> 6] = q; }
  __syncthreads();
  s = ss[0] + ss[1] + ss[2] + ss[3];
  q = sq[0] + sq[1] + sq[2] + sq[3];
  const float mean = s * (1.f / Zq);
  float var = q * (1.f / Zq) - mean * mean;
  var = fmaxf(var, 0.f);
  const float rstd = rsqrtf(var + 1e-5f);
  const float4 g  = ((const float4*)gamma)[t];
  const float4 bb = ((const float4*)beta)[t];
  v.x = (v.x - mean) * rstd * g.x + bb.x;
  v.y = (v.y - mean) * rstd * g.y + bb.y;
  v.z = (v.z - mean) * rstd * g.z + bb.z;
  v.w = (v.w - mean) * rstd * g.w + bb.w;
  ((float4*)o)[t] = v;
}

// ---- fallback (tiny ws): plain f32, correct but slow ----
__global__ __launch_bounds__(256) void fallback_bilinear(
    const float* __restrict__ hd, const float* __restrict__ hp,
    const float* __restrict__ U, const float* __restrict__ V,
    float* __restrict__ out)
{
  const int j  = blockIdx.x * 256 + threadIdx.x;
  const int b0 = blockIdx.y * 8;
  float acc[8] = {0.f, 0.f, 0.f, 0.f, 0.f, 0.f, 0.f, 0.f};
  for (int r = 0; r < Rk; ++r) {
    float u[8] = {0.f}, v[8] = {0.f};
    const float* Up = U + (size_t)r * (D * Zq) + j;
    const float* Vp = V + (size_t)r * (D * Zq) + j;
    for (int k = 0; k < D; ++k) {
      const float uu = Up[(size_t)k * Zq];
      const float vv = Vp[(size_t)k * Zq];
      #pragma unroll
      for (int bi = 0; bi < 8; ++bi) {
        u[bi] = fmaf(hd[(size_t)(b0 + bi) * D + k], uu, u[bi]);
        v[bi] = fmaf(hp[(size_t)(b0 + bi) * D + k], vv, v[bi]);
      }
    }
    #pragma unroll
    for (int bi = 0; bi < 8; ++bi) acc[bi] += u[bi] * v[bi];
  }
  #pragma unroll
  for (int bi = 0; bi < 8; ++bi)
    out[(size_t)(b0 + bi) * Zq + j] = acc[bi];   // raw; ReLU in LN
}

extern "C" void kernel_launch(void* const* d_in, const int* in_sizes, int n_in,
                              void* d_out, int out_size, void* d_ws, size_t ws_size,
                              hipStream_t stream) {
  const float* hd    = (const float*)d_in[0];   // [4096][1024]
  const float* hp    = (const float*)d_in[1];   // [4096][1024]
  const float* U     = (const float*)d_in[2];   // [16][1024][1024]
  const float* V     = (const float*)d_in[3];   // [16][1024][1024]
  const float* gamma = (const float*)d_in[4];   // [1024]
  const float* beta  = (const float*)d_in[5];   // [1024]
  float* out = (float*)d_out;                   // [4096][1024] f32

  const size_t need = 80ull << 20;  // hd,hp fm (16MB) + U,V fm (64MB)
  if (ws_size >= need) {
    u16* hdf = (u16*)d_ws;                   // 4M elems
    u16* hpf = hdf + (size_t)Bq * D;
    u16* Ufm = hpf + (size_t)Bq * D;         // 16M elems each
    u16* Vfm = Ufm + (size_t)Rk * D * Zq;

    fm_pack_A<<<2048, 256, 0, stream>>>(hd, hdf);
    fm_pack_A<<<2048, 256, 0, stream>>>(hp, hpf);
    fm_pack_B<<<8192, 256, 0, stream>>>(U, Ufm);
    fm_pack_B<<<8192, 256, 0, stream>>>(V, Vfm);
    fused_bilinear<0, 1><<<dim3(32, 8), 512, 0, stream>>>(hdf, hpf, Ufm, Vfm, out);
    ln_rows<<<Bq, 256, 0, stream>>>(out, gamma, beta);

    // ---- ablation probes (scratch only; output already finalized) ----
    if (ws_size >= (96ull << 20)) {
      float* scratch = (float*)((char*)d_ws + need);   // 16 MB
      fused_bilinear<1, 2><<<dim3(32, 8), 512, 0, stream>>>(hdf, hpf, Ufm, Vfm, scratch);
      fused_bilinear<2, 2><<<dim3(32, 8), 512, 0, stream>>>(hdf, hpf, Ufm, Vfm, scratch);
    }
  } else {
    fallback_bilinear<<<dim3(Zq / 256, Bq / 8), 256, 0, stream>>>(hd, hp, U, V, out);
    ln_rows<<<Bq, 256, 0, stream>>>(out, gamma, beta);
  }
}

// Round 11
// 351.819 us; speedup vs baseline: 4.7594x; 4.7594x over previous
//
#include <hip/hip_runtime.h>

// MUTAN fused bilinear (low-rank Tucker) + ReLU + LayerNorm, MI355X gfx950.
// Round 11: u/v wave ROLE-SPLIT (waves 0-3: hd*U, waves 4-7: hp*V) +
// mfma_f32_32x32x16_bf16 (wave tile 64x64, 2x2 frags) + all 4 tensors staged
// via global_load_lds (full dedup; VMEM 96->64 KB/step) + rank-boundary
// Hadamard via bf16 LDS exchange into the idle buffer's B-slots.

typedef unsigned short u16;
typedef __attribute__((ext_vector_type(8)))  short bf16x8;   // 8 bf16
typedef __attribute__((ext_vector_type(16))) float f32x16;   // 32x32 MFMA C/D

constexpr int Bq = 4096;   // batch
constexpr int D  = 1024;   // contraction dim
constexpr int Zq = 1024;   // output dim
constexpr int Rk = 16;     // rank
// A pack: [bx(32)][kt(16)][chunk(1024)][8]; chunk = (mfb*4+ks)*64 + lane
//   row = bx*128 + mfb*32 + (l&31), k = kt*64 + ks*16 + 8*(l>>5) + e
// B pack: [r(16)][jt(8)][kt(16)][chunk(1024)][8]; chunk = (nfb*4+ks)*64 + lane
//   col = jt*128 + nfb*32 + (l&31), k likewise
// 32x32x16 frag layouts: A[l&31][8*(l>>5)+e]; B[8*(l>>5)+e][l&31];
// C/D (verified m74/m101): col = lane&31, row = (reg&3)+8*(reg>>2)+4*(lane>>5).

typedef const __attribute__((address_space(1))) void* gas_t;
typedef __attribute__((address_space(3))) void* las_t;

__device__ __forceinline__ u16 f2b(float f) {
  union { float f; unsigned u; } c; c.f = f;
  unsigned r = (c.u + 0x7FFFu + ((c.u >> 16) & 1u)) >> 16;  // RNE
  return (u16)r;
}
__device__ __forceinline__ float b2f(u16 h) {
  union { unsigned u; float f; } c; c.u = ((unsigned)h) << 16; return c.f;
}

// ---- prep: hd/hp [4096][1024] f32 -> fragment-major bf16 (32-row frags) ----
__global__ __launch_bounds__(256) void fm_pack_A(const float* __restrict__ src,
                                                 u16* __restrict__ dst) {
  const int g  = blockIdx.x * 256 + threadIdx.x;      // chunk id (524288)
  const int c  = g & 1023;
  const int kt = (g >> 10) & 15;
  const int bx = g >> 14;
  const int l   = c & 63;
  const int ks  = (c >> 6) & 3;
  const int mfb = c >> 8;                              // 0..3
  const int row = bx * 128 + mfb * 32 + (l & 31);
  const int kb  = kt * 64 + ks * 16 + ((l >> 5) << 3);
  const float* s = src + (size_t)row * D + kb;
  const float4 f0 = *(const float4*)s;
  const float4 f1 = *(const float4*)(s + 4);
  union { u16 h[8]; uint4 u; } o;
  o.h[0] = f2b(f0.x); o.h[1] = f2b(f0.y); o.h[2] = f2b(f0.z); o.h[3] = f2b(f0.w);
  o.h[4] = f2b(f1.x); o.h[5] = f2b(f1.y); o.h[6] = f2b(f1.z); o.h[7] = f2b(f1.w);
  *(uint4*)(dst + (size_t)g * 8) = o.u;
}

// ---- prep: U/V [r][k][z] f32 -> fragment-major bf16 (32-col frags) ----
__global__ __launch_bounds__(256) void fm_pack_B(const float* __restrict__ src,
                                                 u16* __restrict__ dst) {
  const int g  = blockIdx.x * 256 + threadIdx.x;      // chunk id (2097152)
  const int c  = g & 1023;
  const int kt = (g >> 10) & 15;
  const int jt = (g >> 14) & 7;
  const int r  = g >> 17;
  const int l   = c & 63;
  const int ks  = (c >> 6) & 3;
  const int nfb = c >> 8;                              // 0..3
  const int col = jt * 128 + nfb * 32 + (l & 31);
  const int kg  = kt * 64 + ks * 16 + ((l >> 5) << 3);
  const float* s = src + (size_t)r * (D * Zq) + (size_t)kg * Zq + col;
  union { u16 h[8]; uint4 u; } o;
  #pragma unroll
  for (int e = 0; e < 8; ++e) o.h[e] = f2b(s[(size_t)e * Zq]);
  *(uint4*)(dst + (size_t)g * 8) = o.u;
}

#define GLDS(src, dst) __builtin_amdgcn_global_load_lds((gas_t)(src), (las_t)(dst), 16, 0, 0)
#define MFMA32(a, b, c) __builtin_amdgcn_mfma_f32_32x32x16_bf16(a, b, c, 0, 0, 0)

#define STAGE_A(buf, st) do {                                                    \
    const int _kt = (st) & 15;                                                   \
    GLDS(hdp + _kt * 8192 + c0 * 8, &sT[buf][0][c0 * 8]);                        \
    GLDS(hdp + _kt * 8192 + c1 * 8, &sT[buf][0][c1 * 8]);                        \
    GLDS(hpp + _kt * 8192 + c0 * 8, &sT[buf][1][c0 * 8]);                        \
    GLDS(hpp + _kt * 8192 + c1 * 8, &sT[buf][1][c1 * 8]);                        \
  } while (0)

#define STAGE_B(buf, st) do {                                                    \
    const int _kt = (st) & 15;                                                   \
    const u16* _u = Ub + (size_t)((st) >> 4) * rstride + _kt * 8192;             \
    const u16* _v = Vb + (size_t)((st) >> 4) * rstride + _kt * 8192;             \
    GLDS(_u + c0 * 8, &sT[buf][2][c0 * 8]);                                      \
    GLDS(_u + c1 * 8, &sT[buf][2][c1 * 8]);                                      \
    GLDS(_v + c0 * 8, &sT[buf][3][c0 * 8]);                                      \
    GLDS(_v + c1 * 8, &sT[buf][3][c1 * 8]);                                      \
  } while (0)

// role-split compute: each wave reads ONE A tensor + ONE B tensor, 16 MFMA.
#define COMPUTE(buf) do {                                                        \
    const u16* tA = sT[buf][role];                                               \
    const u16* tB = sT[buf][2 + role];                                           \
    _Pragma("unroll")                                                            \
    for (int ks = 0; ks < 4; ++ks) {                                             \
      bf16x8 a0 = *(const bf16x8*)(tA + (((wm * 2 + 0) * 4 + ks) * 64 + lane) * 8); \
      bf16x8 a1 = *(const bf16x8*)(tA + (((wm * 2 + 1) * 4 + ks) * 64 + lane) * 8); \
      bf16x8 b0 = *(const bf16x8*)(tB + (((wn * 2 + 0) * 4 + ks) * 64 + lane) * 8); \
      bf16x8 b1 = *(const bf16x8*)(tB + (((wn * 2 + 1) * 4 + ks) * 64 + lane) * 8); \
      __builtin_amdgcn_s_setprio(1);                                             \
      aw[0][0] = MFMA32(a0, b0, aw[0][0]);                                       \
      aw[0][1] = MFMA32(a0, b1, aw[0][1]);                                       \
      aw[1][0] = MFMA32(a1, b0, aw[1][0]);                                       \
      aw[1][1] = MFMA32(a1, b1, aw[1][1]);                                       \
      __builtin_amdgcn_s_setprio(0);                                             \
    }                                                                            \
  } while (0)

// ---- main: fused bilinear, role-split 32x32x16 MFMA ----
// grid (32 bx, 8 jt) = 256 blocks = 1/CU. 512 thr = 8 waves: 0-3 u-GEMM
// (hd*U), 4-7 v-GEMM (hp*V); wave (wm= (wid&3)>>1, wn = wid&1) owns 64x64.
// Rank-boundary: v-waves publish av (bf16) via LDS, u-waves acc += au*av.
__global__ __launch_bounds__(512, 2) void fused_bilinear(
    const u16* __restrict__ hdf, const u16* __restrict__ hpf,
    const u16* __restrict__ Uf, const u16* __restrict__ Vf,
    float* __restrict__ out)
{
  __shared__ __align__(16) u16 sT[2][4][8192];   // 128 KB: [buf][hd,hp,U,V]

  const int tid  = threadIdx.x;
  const int lane = tid & 63;
  const int wid  = tid >> 6;
  const int role = wid >> 2;              // 0 = u (hd*U), 1 = v (hp*V)
  const int w4   = wid & 3;
  const int wm   = w4 >> 1;               // 0..1
  const int wn   = w4 & 1;                // 0..1

  const int bx = blockIdx.x;              // 0..31 (XCD = bx%8)
  const int jt = blockIdx.y;              // 0..7

  const u16* hdp = hdf + (size_t)bx * 16 * 8192;     // [kt][1024 chunks][8]
  const u16* hpp = hpf + (size_t)bx * 16 * 8192;
  const u16* Ub  = Uf + (size_t)jt * 16 * 8192;      // + r*rstride + kt*8192
  const u16* Vb  = Vf + (size_t)jt * 16 * 8192;
  const size_t rstride = (size_t)8 * 16 * 8192;

  const int c0 = tid;                     // staging chunks per tensor
  const int c1 = tid + 512;

  f32x16 acc[2][2], aw[2][2];
  #pragma unroll
  for (int mf = 0; mf < 2; ++mf)
    #pragma unroll
    for (int nf = 0; nf < 2; ++nf) {
      #pragma unroll
      for (int i = 0; i < 16; ++i) { acc[mf][nf][i] = 0.f; aw[mf][nf][i] = 0.f; }
    }

  // exchange buffer: B-slots of buf 0 (boundary steps are odd -> buf 1 active)
  unsigned* exch = (unsigned*)&sT[0][2][0];          // 8192 u32 = 32 KB

  // prologue: stage step 0 into buf 0.
  STAGE_A(0, 0);
  STAGE_B(0, 0);
  __syncthreads();

  #pragma unroll 1
  for (int it = 0; it < 128; ++it) {
    const int s0 = it * 2;
    const int s1 = s0 + 1;

    // even step: compute buf 0, stage s1 into buf 1
    STAGE_A(1, s1);
    STAGE_B(1, s1);
    COMPUTE(0);
    __syncthreads();

    // odd step: compute buf 1, stage s1+1 into buf 0
    const bool bound = ((s1 & 15) == 15);
    if (s1 < 255) {
      STAGE_A(0, s1 + 1);
      if (!bound) STAGE_B(0, s1 + 1);
    }
    COMPUTE(1);
    if (bound) {
      __syncthreads();                 // buf-0 reads (prev even step) long done;
                                       // buf-1 reads done; exch region idle
      if (role) {                      // v-waves: publish av as bf16
        #pragma unroll
        for (int mf = 0; mf < 2; ++mf)
          #pragma unroll
          for (int nf = 0; nf < 2; ++nf) {
            const int f = mf * 2 + nf;
            #pragma unroll
            for (int rp = 0; rp < 8; ++rp) {
              const unsigned lo = f2b(aw[mf][nf][2 * rp]);
              const unsigned hi = f2b(aw[mf][nf][2 * rp + 1]);
              exch[((w4 * 4 + f) * 8 + rp) * 64 + lane] = lo | (hi << 16);
            }
          }
      }
      __syncthreads();
      if (!role) {                     // u-waves: acc += au * av
        #pragma unroll
        for (int mf = 0; mf < 2; ++mf)
          #pragma unroll
          for (int nf = 0; nf < 2; ++nf) {
            const int f = mf * 2 + nf;
            #pragma unroll
            for (int rp = 0; rp < 8; ++rp) {
              const unsigned w = exch[((w4 * 4 + f) * 8 + rp) * 64 + lane];
              acc[mf][nf][2 * rp]     += aw[mf][nf][2 * rp]     * b2f((u16)(w & 0xFFFFu));
              acc[mf][nf][2 * rp + 1] += aw[mf][nf][2 * rp + 1] * b2f((u16)(w >> 16));
            }
          }
      }
      #pragma unroll
      for (int mf = 0; mf < 2; ++mf)
        #pragma unroll
        for (int nf = 0; nf < 2; ++nf)
          #pragma unroll
          for (int i = 0; i < 16; ++i) aw[mf][nf][i] = 0.f;
      __syncthreads();                 // exchange consumed; exch region free
      if (s1 < 255) STAGE_B(0, s1 + 1);
      __syncthreads();                 // drain late B stage (+ pending A stage)
    } else {
      __syncthreads();
    }
  }

  // epilogue: u-waves store RAW rank-sum (ReLU in LN).
  // D-layout 32x32: col = lane&31, row = (reg&3) + 8*(reg>>2) + 4*(lane>>5).
  if (!role) {
    const int brow = bx * 128 + wm * 64;
    const int jcol = jt * 128 + wn * 64;
    #pragma unroll
    for (int mf = 0; mf < 2; ++mf)
      #pragma unroll
      for (int nf = 0; nf < 2; ++nf) {
        #pragma unroll
        for (int i = 0; i < 16; ++i) {
          const int row = brow + mf * 32 + (i & 3) + 8 * (i >> 2) + 4 * (lane >> 5);
          const int col = jcol + nf * 32 + (lane & 31);
          out[(size_t)row * Zq + col] = acc[mf][nf][i];
        }
      }
  }
}

// ---- LayerNorm: z = relu(p); LN(z) -> out, in place. jnp.var ddof=0. ----
__global__ __launch_bounds__(256) void ln_rows(float* __restrict__ out,
    const float* __restrict__ gamma, const float* __restrict__ beta)
{
  const int row = blockIdx.x;
  const int t = threadIdx.x;
  float* o = out + (size_t)row * Zq;
  float4 v = ((const float4*)o)[t];
  v.x = fmaxf(v.x, 0.f); v.y = fmaxf(v.y, 0.f);
  v.z = fmaxf(v.z, 0.f); v.w = fmaxf(v.w, 0.f);
  float s = v.x + v.y + v.z + v.w;
  float q = v.x * v.x + v.y * v.y + v.z * v.z + v.w * v.w;
  #pragma unroll
  for (int off = 32; off > 0; off >>= 1) {
    s += __shfl_xor(s, off);
    q += __shfl_xor(q, off);
  }
  __shared__ float ss[4], sq[4];
  if ((t & 63) == 0) { ss[t >> 6] = s; sq[t >> 6] = q; }
  __syncthreads();
  s = ss[0] + ss[1] + ss[2] + ss[3];
  q = sq[0] + sq[1] + sq[2] + sq[3];
  const float mean = s * (1.f / Zq);
  float var = q * (1.f / Zq) - mean * mean;
  var = fmaxf(var, 0.f);
  const float rstd = rsqrtf(var + 1e-5f);
  const float4 g  = ((const float4*)gamma)[t];
  const float4 bb = ((const float4*)beta)[t];
  v.x = (v.x - mean) * rstd * g.x + bb.x;
  v.y = (v.y - mean) * rstd * g.y + bb.y;
  v.z = (v.z - mean) * rstd * g.z + bb.z;
  v.w = (v.w - mean) * rstd * g.w + bb.w;
  ((float4*)o)[t] = v;
}

// ---- fallback (tiny ws): plain f32, correct but slow ----
__global__ __launch_bounds__(256) void fallback_bilinear(
    const float* __restrict__ hd, const float* __restrict__ hp,
    const float* __restrict__ U, const float* __restrict__ V,
    float* __restrict__ out)
{
  const int j  = blockIdx.x * 256 + threadIdx.x;
  const int b0 = blockIdx.y * 8;
  float acc[8] = {0.f, 0.f, 0.f, 0.f, 0.f, 0.f, 0.f, 0.f};
  for (int r = 0; r < Rk; ++r) {
    float u[8] = {0.f}, v[8] = {0.f};
    const float* Up = U + (size_t)r * (D * Zq) + j;
    const float* Vp = V + (size_t)r * (D * Zq) + j;
    for (int k = 0; k < D; ++k) {
      const float uu = Up[(size_t)k * Zq];
      const float vv = Vp[(size_t)k * Zq];
      #pragma unroll
      for (int bi = 0; bi < 8; ++bi) {
        u[bi] = fmaf(hd[(size_t)(b0 + bi) * D + k], uu, u[bi]);
        v[bi] = fmaf(hp[(size_t)(b0 + bi) * D + k], vv, v[bi]);
      }
    }
    #pragma unroll
    for (int bi = 0; bi < 8; ++bi) acc[bi] += u[bi] * v[bi];
  }
  #pragma unroll
  for (int bi = 0; bi < 8; ++bi)
    out[(size_t)(b0 + bi) * Zq + j] = acc[bi];   // raw; ReLU in LN
}

extern "C" void kernel_launch(void* const* d_in, const int* in_sizes, int n_in,
                              void* d_out, int out_size, void* d_ws, size_t ws_size,
                              hipStream_t stream) {
  const float* hd    = (const float*)d_in[0];   // [4096][1024]
  const float* hp    = (const float*)d_in[1];   // [4096][1024]
  const float* U     = (const float*)d_in[2];   // [16][1024][1024]
  const float* V     = (const float*)d_in[3];   // [16][1024][1024]
  const float* gamma = (const float*)d_in[4];   // [1024]
  const float* beta  = (const float*)d_in[5];   // [1024]
  float* out = (float*)d_out;                   // [4096][1024] f32

  const size_t need = 80ull << 20;  // hd,hp fm (16MB) + U,V fm (64MB)
  if (ws_size >= need) {
    u16* hdf = (u16*)d_ws;                   // 4M elems
    u16* hpf = hdf + (size_t)Bq * D;
    u16* Ufm = hpf + (size_t)Bq * D;         // 16M elems each
    u16* Vfm = Ufm + (size_t)Rk * D * Zq;

    fm_pack_A<<<2048, 256, 0, stream>>>(hd, hdf);
    fm_pack_A<<<2048, 256, 0, stream>>>(hp, hpf);
    fm_pack_B<<<8192, 256, 0, stream>>>(U, Ufm);
    fm_pack_B<<<8192, 256, 0, stream>>>(V, Vfm);
    fused_bilinear<<<dim3(32, 8), 512, 0, stream>>>(hdf, hpf, Ufm, Vfm, out);
  } else {
    fallback_bilinear<<<dim3(Zq / 256, Bq / 8), 256, 0, stream>>>(hd, hp, U, V, out);
  }
  ln_rows<<<Bq, 256, 0, stream>>>(out, gamma, beta);
}